// Round 4
// baseline (32143.539 us; speedup 1.0000x reference)
//
#include <hip/hip_runtime.h>
#include <cstdint>
#include <cstddef>

#define B_    64
#define T_    1024
#define D_    256
#define H_    512
#define BU_   512
#define GRID_ 256
#define NT_   512
#define NW_   8     // waves per block
#define RPB_  16    // rows per block (4 row-groups)

__device__ __forceinline__ float fsigmoid(float x) { return 1.f / (1.f + __expf(-x)); }
__device__ __forceinline__ float ftanh(float x)    { return 2.f / (1.f + __expf(-2.f * x)) - 1.f; }

// Relaxed agent-scope atomic store: write-through (sc0 sc1), visible at the
// L3 coherence point once vmcnt-acked, never dirty in any L2.
__device__ __forceinline__ void astore(float* p, float v) {
  union { float f; unsigned u; } c; c.f = v;
  __hip_atomic_store((unsigned*)p, c.u, __ATOMIC_RELAXED, __HIP_MEMORY_SCOPE_AGENT);
}
__device__ __forceinline__ unsigned aload(const unsigned* p) {
  return __hip_atomic_load(p, __ATOMIC_RELAXED, __HIP_MEMORY_SCOPE_AGENT);
}

// Contention-free flat barrier: each block STORES tag into its own slot
// (no RMW, no serialization); wave 0 of every block polls all 256 slots
// (4 dword agent-loads per lane) until all >= tag. Tags are monotone, so a
// block racing one phase ahead (slot == tag+1) is correctly counted.
// Ordering: per-wave s_waitcnt vmcnt(0) drains data stores; __syncthreads
// joins all waves; tid0's slot store is thus ordered after all block data.
// After detection: one buffer_inv sc1 (drop stale clean lines from L1/L2;
// dirty out-lines preserved), then cached loads see fresh data.
__device__ __forceinline__ void grid_barrier(unsigned* slots, unsigned tag) {
  asm volatile("s_waitcnt vmcnt(0)" ::: "memory");
  __syncthreads();
  const int tid = threadIdx.x;
  if (tid < 64) {
    if (tid == 0)
      __hip_atomic_store(slots + blockIdx.x, tag, __ATOMIC_RELAXED, __HIP_MEMORY_SCOPE_AGENT);
    const unsigned* s4 = slots + tid * 4;
    for (;;) {
      unsigned a0 = aload(s4 + 0), a1 = aload(s4 + 1);
      unsigned a2 = aload(s4 + 2), a3 = aload(s4 + 3);
      int ok = (a0 >= tag) & (a1 >= tag) & (a2 >= tag) & (a3 >= tag);
      if (__all(ok)) break;
      __builtin_amdgcn_s_sleep(2);
    }
    asm volatile("buffer_inv sc1\n\ts_waitcnt vmcnt(0)" ::: "memory");
  }
  __syncthreads();
}

__global__ __launch_bounds__(NT_, 2) void cfc_kernel(
    const float* __restrict__ x,    const float* __restrict__ ts,
    const float* __restrict__ h0,   const float* __restrict__ s0,
    const float* __restrict__ Wbb,  const float* __restrict__ bbb,
    const float* __restrict__ Wff1, const float* __restrict__ bff1,
    const float* __restrict__ Wff2, const float* __restrict__ bff2,
    const float* __restrict__ Wta,  const float* __restrict__ bta,
    const float* __restrict__ Wtb,  const float* __restrict__ btb,
    float* __restrict__ out, float* __restrict__ hws,
    float* __restrict__ bbws, unsigned* __restrict__ slots)
{
  __shared__ float part[NW_][16][66];  // 33792 B, stride 66 -> conflict-free
  __shared__ float sums[NW_][64];      //  2048 B
  __shared__ float sloc[RPB_][NW_];    //   512 B

  const int tid  = threadIdx.x;
  const int w    = tid >> 6;      // wave 0..7 -> owns one output column
  const int lane = tid & 63;
  const int bid  = blockIdx.x;
  const int r    = bid >> 6;      // row-group 0..3: rows 16r..16r+15
  const int c    = bid & 63;      // col-block:      cols 8c..8c+7
  const int col  = c * 8 + w;     // this wave's column
  const int row0 = r * 16;

  // ---- per-wave weight column into registers (44 floats/lane).
  // K mapping: k = i*256 + lane*4 + e  (i=0: x part; i=1,2: h halves).
  float w1[3][4];
  #pragma unroll
  for (int i = 0; i < 3; ++i)
    #pragma unroll
    for (int e = 0; e < 4; ++e)
      w1[i][e] = Wbb[(size_t)(i * 256 + lane * 4 + e) * BU_ + col];

  float w2[4][2][4];
  const float* Wm[4] = {Wff1, Wff2, Wta, Wtb};
  #pragma unroll
  for (int m = 0; m < 4; ++m)
    #pragma unroll
    for (int i = 0; i < 2; ++i)
      #pragma unroll
      for (int e = 0; e < 4; ++e)
        w2[m][i][e] = Wm[m][(size_t)(i * 256 + lane * 4 + e) * H_ + col];

  const float bB  = bbb[col];
  const float b1  = bff1[col];
  const float b2  = bff2[col];
  const float ba  = bta[col];
  const float bb2 = btb[col];

  // ---- init: blocks c<16 stage h0 row (16r+c); everyone stages its s slice.
  if (c < 16) {
    const int row = row0 + c;
    astore(hws + (size_t)row * H_ + tid, h0[(size_t)row * H_ + tid]);
  }
  if (tid < 128) {
    const int rl = tid >> 3, cw = tid & 7;
    sloc[rl][cw] = s0[(size_t)(row0 + rl) * H_ + c * 8 + cw];
  }
  grid_barrier(slots, 1u);

  for (int t = 0; t < T_; ++t) {
    // ========== Phase 1: bb[rows, col] = silu(z @ Wbb + bbb) ==========
    float p[16];
    #pragma unroll
    for (int rl = 0; rl < 16; ++rl) {
      const int row = row0 + rl;
      const float4 zx = ((const float4*)(x + ((size_t)row * T_ + t) * D_))[lane];
      const float4* h4 = (const float4*)(hws + (size_t)row * H_);
      const float4 zh0 = h4[lane];
      const float4 zh1 = h4[lane + 64];
      // Deferred coalesced out-write: block (r, c<16), wave 0 holds a FULL
      // h(t-1) row across its lanes -> two full-line float4 stores.
      if (w == 0 && rl == c && t > 0) {  // rl==c only possible when c<16
        float4* op = (float4*)(out + ((size_t)row * T_ + (t - 1)) * H_);
        op[lane]      = zh0;
        op[lane + 64] = zh1;
      }
      float a;
      a  = zx.x  * w1[0][0]; a += zx.y  * w1[0][1];
      a += zx.z  * w1[0][2]; a += zx.w  * w1[0][3];
      a += zh0.x * w1[1][0]; a += zh0.y * w1[1][1];
      a += zh0.z * w1[1][2]; a += zh0.w * w1[1][3];
      a += zh1.x * w1[2][0]; a += zh1.y * w1[2][1];
      a += zh1.z * w1[2][2]; a += zh1.w * w1[2][3];
      p[rl] = a;
    }

    #pragma unroll
    for (int o = 0; o < 16; ++o) part[w][o][lane] = p[o];
    if (lane < 16) {
      const float2* pp = (const float2*)(&part[w][lane][0]);
      float se = 0.f, so = 0.f;
      #pragma unroll
      for (int i = 0; i < 32; ++i) { float2 v = pp[i]; se += v.x; so += v.y; }
      const float pre = se + so + bB;
      const float bbv = pre * fsigmoid(pre);
      astore(bbws + (size_t)(row0 + lane) * BU_ + col, bbv);
    }
    grid_barrier(slots, 2u * t + 2u);  // bb at L3, caches invalidated

    // ========== Phase 2: four mats + recurrence for (rows, col) ==========
    #pragma unroll
    for (int b = 0; b < 4; ++b) {
      float q[16];  // o = rr*4 + m
      #pragma unroll
      for (int rr = 0; rr < 4; ++rr) {
        const int row = row0 + b * 4 + rr;
        const float4* bb4 = (const float4*)(bbws + (size_t)row * BU_);
        const float4 v0 = bb4[lane];
        const float4 v1 = bb4[lane + 64];
        #pragma unroll
        for (int m = 0; m < 4; ++m) {
          float a;
          a  = v0.x * w2[m][0][0]; a += v0.y * w2[m][0][1];
          a += v0.z * w2[m][0][2]; a += v0.w * w2[m][0][3];
          a += v1.x * w2[m][1][0]; a += v1.y * w2[m][1][1];
          a += v1.z * w2[m][1][2]; a += v1.w * w2[m][1][3];
          q[rr * 4 + m] = a;
        }
      }
      #pragma unroll
      for (int o = 0; o < 16; ++o) part[w][o][lane] = q[o];
      if (lane < 16) {
        const float2* pp = (const float2*)(&part[w][lane][0]);
        float se = 0.f, so = 0.f;
        #pragma unroll
        for (int i = 0; i < 32; ++i) { float2 v = pp[i]; se += v.x; so += v.y; }
        sums[w][b * 16 + lane] = se + so;  // index = (b*4+rr)*4 + m = rl*4 + m
      }
    }

    if (lane < 16) {
      const int rl  = lane;
      const int row = row0 + rl;
      const float4 Sm = *(const float4*)&sums[w][rl * 4];
      const float tsv = ts[(size_t)row * T_ + t];
      const float tsn = 1.f / tsv;  // ts in [0.5, 2] -> always > 0
      const float wts = __expf(tsn * (1.f - 2.f * __logf(tsn)));
      const float f1  = ftanh(Sm.x + b1);
      const float f2  = ftanh(Sm.y + b2);
      float sv = sloc[rl][w] + (Sm.z + ba) * wts + (Sm.w + bb2);
      sloc[rl][w] = sv;
      const float ti = fsigmoid(sv);
      const float hn = f1 + ti * (f2 - f1);
      astore(hws + (size_t)row * H_ + col, hn);
    }
    grid_barrier(slots, 2u * t + 3u);  // h at L3, caches invalidated
  }

  // Tail: out[:, T-1, :]
  if (c < 16 && w == 0) {
    const int row = row0 + c;
    const float4* h4 = (const float4*)(hws + (size_t)row * H_);
    const float4 a0 = h4[lane];
    const float4 a1 = h4[lane + 64];
    float4* op = (float4*)(out + ((size_t)row * T_ + (T_ - 1)) * H_);
    op[lane]      = a0;
    op[lane + 64] = a1;
  }
}

extern "C" void kernel_launch(void* const* d_in, const int* in_sizes, int n_in,
                              void* d_out, int out_size, void* d_ws, size_t ws_size,
                              hipStream_t stream) {
  const float* x    = (const float*)d_in[0];
  const float* ts   = (const float*)d_in[1];
  const float* h0   = (const float*)d_in[2];
  const float* s0   = (const float*)d_in[3];
  const float* Wbb  = (const float*)d_in[4];
  const float* bbb  = (const float*)d_in[5];
  const float* Wff1 = (const float*)d_in[6];
  const float* bff1 = (const float*)d_in[7];
  const float* Wff2 = (const float*)d_in[8];
  const float* bff2 = (const float*)d_in[9];
  const float* Wta  = (const float*)d_in[10];
  const float* bta  = (const float*)d_in[11];
  const float* Wtb  = (const float*)d_in[12];
  const float* btb  = (const float*)d_in[13];
  float* out = (float*)d_out;

  // ws layout: [0,4096): slot array (256 x u32 used); then h (128 KB); bb (128 KB).
  unsigned* slots = (unsigned*)d_ws;
  float* hws  = (float*)((char*)d_ws + 4096);
  float* bbws = hws + B_ * H_;

  hipMemsetAsync(d_ws, 0, 4096, stream);  // tags start at 1

  void* args[] = {
      (void*)&x, (void*)&ts, (void*)&h0, (void*)&s0,
      (void*)&Wbb, (void*)&bbb, (void*)&Wff1, (void*)&bff1,
      (void*)&Wff2, (void*)&bff2, (void*)&Wta, (void*)&bta,
      (void*)&Wtb, (void*)&btb, (void*)&out, (void*)&hws,
      (void*)&bbws, (void*)&slots};

  hipLaunchCooperativeKernel((const void*)cfc_kernel, dim3(GRID_), dim3(NT_),
                             args, 0, stream);
}